// Round 1
// baseline (614.675 us; speedup 1.0000x reference)
//
#include <hip/hip_runtime.h>
#include <math.h>

#define NAGENT 10
#define OBS_D  64
#define HID    50
#define NSYM   10
#define NACT   2
#define KSTEPS 2
#define NEGV   (-1e9f)
#define INF    (HID + NSYM + HID)   // 110

#define BPB 6                // batch elements per block
#define TPB 64               // one wave
#define AG  (BPB * NAGENT)   // 60 active lanes

#define WENC_LD 52           // padded row stride (16B aligned rows)
#define WF_LD   52

// smem layout (floats):
//   obs staging: [0, AG*65) = [0,3900)   (dead after phase 1)
//   h0:          [0, AG*51) = [0,3060)   (written after obs dead)
//   h1:          [3060, 6120)
//   c:           [6120, 6120+60)
#define SM_H1  (AG*51)        // 3060
#define SM_C   (2*AG*51)      // 6120
#define SM_TOT (SM_C + BPB*NSYM + 16)

__device__ __forceinline__ float fast_tanh(float x) {
  float xc = fminf(15.f, fmaxf(-15.f, x));
  float e  = __expf(2.f * xc);
  return __fdividef(e - 1.f, e + 1.f);
}

__global__ void prep_weights(const float* __restrict__ W_enc,
                             const float* __restrict__ W_f,
                             float* __restrict__ ws) {
  int i = blockIdx.x * blockDim.x + threadIdx.x;
  const int nEnc = OBS_D * WENC_LD;          // 3328
  const int nF   = KSTEPS * INF * WF_LD;     // 11440
  if (i < nEnc) {
    int k = i / WENC_LD, j = i % WENC_LD;
    ws[i] = (j < HID) ? W_enc[k*HID + j] : 0.f;
  } else if (i < nEnc + nF) {
    int r = i - nEnc;
    int s = r / (INF*WF_LD);
    int rem = r % (INF*WF_LD);
    int k = rem / WF_LD, j = rem % WF_LD;
    ws[i] = (j < HID) ? W_f[(s*INF + k)*HID + j] : 0.f;
  }
}

__global__ __launch_bounds__(TPB) void policy_kernel(
    const float* __restrict__ obs,
    const float* __restrict__ mask,
    const float* __restrict__ b_enc,
    const float* __restrict__ b_f,
    const float* __restrict__ W_comm,
    const float* __restrict__ b_comm,
    const float* __restrict__ W_pi,
    const float* __restrict__ b_pi,
    const float* __restrict__ W_v,
    const float* __restrict__ b_v,
    const float* __restrict__ W_encP,
    const float* __restrict__ W_fP,
    float* __restrict__ out,
    int B)
{
  __shared__ float smem[SM_TOT];
  const int t   = threadIdx.x;
  const int be0 = blockIdx.x * BPB;
  const int nbe = min(BPB, B - be0);
  const int nag = nbe * NAGENT;
  const int g0  = be0 * NAGENT;
  const bool act = (t < nag);
  const int ta  = act ? t : 0;                 // clamped for safe LDS reads
  const int bel = act ? (t / NAGENT) : 0;
  const long long g = (long long)g0 + t;
  const long long NA = (long long)B * NAGENT;

  // ---- stage obs -> smem[a*65 + k] (coalesced float4 reads)
  {
    const float4* o4 = (const float4*)(obs + (long long)g0 * OBS_D);
    const int n4 = nag * (OBS_D/4);
    for (int idx = t; idx < n4; idx += TPB) {
      float4 v = o4[idx];
      int a = idx >> 4;
      int k = (idx & 15) << 2;
      float* p = &smem[a*65 + k];
      p[0]=v.x; p[1]=v.y; p[2]=v.z; p[3]=v.w;
    }
  }
  __syncthreads();

  // ---- phase 1: h0 = tanh(obs @ W_enc + b_enc)
  float acc[HID];
  #pragma unroll
  for (int j=0;j<HID;j++) acc[j] = b_enc[j];
  {
    const int a65 = ta * 65;
    #pragma unroll 4
    for (int k=0;k<OBS_D;k++){
      float x = smem[a65 + k];
      const float* wr = &W_encP[k*WENC_LD];
      #pragma unroll
      for (int j=0;j<HID;j++) acc[j] = fmaf(x, wr[j], acc[j]);
    }
  }
  float hr[HID];
  #pragma unroll
  for (int j=0;j<HID;j++) hr[j] = fast_tanh(acc[j]);
  __syncthreads();                 // all obs reads done before overwrite
  if (act){
    #pragma unroll
    for (int j=0;j<HID;j++) smem[t*51 + j] = hr[j];   // h0
  }
  // (visibility of h0 writes is ordered by the c-aggregation barriers below)

  const float mk = act ? mask[g] : 1.f;
  float clp = 0.f;
  float c_reg[NSYM];

  #pragma unroll
  for (int i=0;i<KSTEPS;i++){
    // ---- comm head on hr (registers, static)
    float cl[NSYM];
    #pragma unroll
    for (int s=0;s<NSYM;s++) cl[s] = b_comm[s];
    #pragma unroll
    for (int k=0;k<HID;k++){
      #pragma unroll
      for (int s=0;s<NSYM;s++) cl[s] = fmaf(hr[k], W_comm[k*NSYM+s], cl[s]);
    }
    if (mk == 0.f){
      #pragma unroll
      for (int s=0;s<NSYM;s++) cl[s] = NEGV;
    }
    int w = 0; float best = cl[0];
    #pragma unroll
    for (int s=1;s<NSYM;s++){ if (cl[s] > best){ best = cl[s]; w = s; } }
    float se = 0.f;
    #pragma unroll
    for (int s=0;s<NSYM;s++) se += __expf(cl[s] - best);
    clp += (-__logf(se)) * mk;     // log_softmax at argmax = -log(sum)

    // ---- c aggregation across the 10 agents of each batch element
    if (t < BPB*NSYM) smem[SM_C + t] = 0.f;
    __syncthreads();
    if (act) smem[SM_C + bel*NSYM + w] = 1.0f;   // same-value race is benign
    __syncthreads();
    #pragma unroll
    for (int s=0;s<NSYM;s++) c_reg[s] = smem[SM_C + bel*NSYM + s];

    // ---- h' = tanh([h, c, h0] @ W_f[i] + b_f[i])
    #pragma unroll
    for (int j=0;j<HID;j++) acc[j] = b_f[i*HID + j];
    #pragma unroll
    for (int s=0;s<NSYM;s++){
      const float cv = c_reg[s];
      const float* wr = &W_fP[(i*INF + HID + s)*WF_LD];
      #pragma unroll
      for (int j=0;j<HID;j++) acc[j] = fmaf(cv, wr[j], acc[j]);
    }
    const int a51 = ta*51;
    if (i == 0){
      #pragma unroll 2
      for (int k=0;k<HID;k++){
        float x = smem[a51 + k];                       // h == h0 at step 0
        const float* wa = &W_fP[(k)*WF_LD];
        const float* wd = &W_fP[(HID + NSYM + k)*WF_LD];
        #pragma unroll
        for (int j=0;j<HID;j++) acc[j] = fmaf(x, wa[j], acc[j]);
        #pragma unroll
        for (int j=0;j<HID;j++) acc[j] = fmaf(x, wd[j], acc[j]);
      }
    } else {
      #pragma unroll 2
      for (int k=0;k<HID;k++){
        float xa = smem[SM_H1 + a51 + k];              // h1
        float xd = smem[a51 + k];                      // h0
        const float* wa = &W_fP[(INF + k)*WF_LD];
        const float* wd = &W_fP[(INF + HID + NSYM + k)*WF_LD];
        #pragma unroll
        for (int j=0;j<HID;j++) acc[j] = fmaf(xa, wa[j], acc[j]);
        #pragma unroll
        for (int j=0;j<HID;j++) acc[j] = fmaf(xd, wd[j], acc[j]);
      }
    }
    #pragma unroll
    for (int j=0;j<HID;j++) hr[j] = fast_tanh(acc[j]);
    if (i == 0){
      if (act){
        #pragma unroll
        for (int j=0;j<HID;j++) smem[SM_H1 + t*51 + j] = hr[j];
      }
      // next iteration's c-aggregation barriers order these writes
    }
  }

  // ---- heads (hr = h2, registers)
  float l0 = b_pi[0], l1 = b_pi[1], bv = b_v[0];
  #pragma unroll
  for (int k=0;k<HID;k++){
    l0 = fmaf(hr[k], W_pi[k*NACT+0], l0);
    l1 = fmaf(hr[k], W_pi[k*NACT+1], l1);
    bv = fmaf(hr[k], W_v[k], bv);
  }
  if (act){
    const float lo0 = (mk==0.f) ? NEGV : l0;
    const float lo1 = (mk==0.f) ? NEGV : l1;
    out[g*2    ] = lo0;
    out[g*2 + 1] = lo1;
    out[NA*2 + g] = bv * mk;       // baseline
    out[NA*3 + g] = clp;           // comm_logp
    #pragma unroll
    for (int s=0;s<NSYM;s++) out[NA*4 + g*NSYM + s] = c_reg[s];
  }
}

extern "C" void kernel_launch(void* const* d_in, const int* in_sizes, int n_in,
                              void* d_out, int out_size, void* d_ws, size_t ws_size,
                              hipStream_t stream) {
  const float* obs    = (const float*)d_in[0];
  const float* mask   = (const float*)d_in[1];
  const float* W_enc  = (const float*)d_in[2];
  const float* b_enc  = (const float*)d_in[3];
  const float* W_f    = (const float*)d_in[4];
  const float* b_f    = (const float*)d_in[5];
  const float* W_comm = (const float*)d_in[6];
  const float* b_comm = (const float*)d_in[7];
  const float* W_pi   = (const float*)d_in[8];
  const float* b_pi   = (const float*)d_in[9];
  const float* W_v    = (const float*)d_in[10];
  const float* b_v    = (const float*)d_in[11];
  float* out = (float*)d_out;
  float* ws  = (float*)d_ws;

  const int B  = in_sizes[0] / (NAGENT * OBS_D);
  const int nP = OBS_D*WENC_LD + KSTEPS*INF*WF_LD;   // 14768 floats in d_ws

  hipLaunchKernelGGL(prep_weights, dim3((nP + 255)/256), dim3(256), 0, stream,
                     W_enc, W_f, ws);

  const int grid = (B + BPB - 1) / BPB;
  hipLaunchKernelGGL(policy_kernel, dim3(grid), dim3(TPB), 0, stream,
                     obs, mask, b_enc, b_f, W_comm, b_comm, W_pi, b_pi, W_v, b_v,
                     ws, ws + OBS_D*WENC_LD, out, B);
}

// Round 2
// 535.058 us; speedup vs baseline: 1.1488x; 1.1488x over previous
//
#include <hip/hip_runtime.h>
#include <math.h>

#define NAGENT 10
#define OBS_D  64
#define HID    50
#define NSYM   10
#define NACT   2
#define NEGV   (-1e9f)

#define BPB 6                // batch elements per block
#define TPB 64               // one wave, zero barriers
#define AG  (BPB * NAGENT)   // 60 active lanes

#define LD 52                // padded weight row stride (16B-aligned rows)

// ws layout (floats), all rows padded to LD=52:
//  WencP [64][52] @ 0      : W_enc rows
//  WC0   [50][52] @ 3328   : W_f0[h] + W_f0[skip] rows (both multiply h0 at step 0)
//  W1S   [50][52] @ 5928   : W_f1[skip] rows
//  W1H   [50][52] @ 8528   : W_f1[h] rows
//  WC0c  [10][52] @ 11128  : W_f0[c] rows
//  W1c   [10][52] @ 11648  : W_f1[c] rows
#define OFF_WC0  3328
#define OFF_W1S  5928
#define OFF_W1H  8528
#define OFF_WC0c 11128
#define OFF_W1c  11648
#define NPREP    (234 * LD)   // 12168

__device__ __forceinline__ float fast_tanh(float x) {
  float xc = fminf(15.f, fmaxf(-15.f, x));
  float e  = __expf(2.f * xc);
  return __fdividef(e - 1.f, e + 1.f);
}

__global__ void prep_weights(const float* __restrict__ W_enc,
                             const float* __restrict__ W_f,
                             float* __restrict__ ws) {
  int i = blockIdx.x * blockDim.x + threadIdx.x;
  if (i >= NPREP) return;
  int j = i % LD;
  int r = i / LD;
  float v = 0.f;
  if (j < HID) {
    if      (r <  64)                { v = W_enc[r*HID + j]; }
    else if (r < 114) { int k=r-64;    v = W_f[k*HID + j] + W_f[(60+k)*HID + j]; }
    else if (r < 164) { int k=r-114;   v = W_f[(110+60+k)*HID + j]; }
    else if (r < 214) { int k=r-164;   v = W_f[(110+k)*HID + j]; }
    else if (r < 224) { int s=r-214;   v = W_f[(50+s)*HID + j]; }
    else              { int s=r-224;   v = W_f[(110+50+s)*HID + j]; }
  }
  ws[i] = v;
}

// masked log-softmax argmax step: applies mask to cl[], returns argmax,
// accumulates comm_logp contribution into clp.
__device__ __forceinline__ int comm_pick(float cl[NSYM], float mk, float& clp) {
  #pragma unroll
  for (int s = 0; s < NSYM; s++) cl[s] = (mk == 0.f) ? NEGV : cl[s];
  int w = 0; float best = cl[0];
  #pragma unroll
  for (int s = 1; s < NSYM; s++) { bool b = cl[s] > best; best = b ? cl[s] : best; w = b ? s : w; }
  float se = 0.f;
  #pragma unroll
  for (int s = 0; s < NSYM; s++) se += __expf(cl[s] - best);
  clp += (-__logf(se)) * mk;      // log_softmax at argmax = -log(sum exp(cl-best))
  return w;
}

__global__ __launch_bounds__(TPB, 4) void policy_kernel(
    const float* __restrict__ obs,
    const float* __restrict__ mask,
    const float* __restrict__ b_enc,
    const float* __restrict__ b_f,
    const float* __restrict__ W_comm,
    const float* __restrict__ b_comm,
    const float* __restrict__ W_pi,
    const float* __restrict__ b_pi,
    const float* __restrict__ W_v,
    const float* __restrict__ b_v,
    const float* __restrict__ wsP,
    float* __restrict__ out,
    int B)
{
  __shared__ float hbuf[AG * 51];          // lane-private h rows, stride 51 (odd -> conflict-free)
  const int t   = threadIdx.x;
  const int be0 = blockIdx.x * BPB;
  const int nbe = min(BPB, B - be0);
  const int nag = nbe * NAGENT;
  const bool act = (t < nag);
  const int bel = t / NAGENT;              // batch-element-in-block (garbage-safe for inactive)
  const long long NA = (long long)B * NAGENT;
  const long long g  = (long long)be0 * NAGENT + t;
  const long long gc = act ? g : (NA - 1); // clamped for safe global reads
  const int sl = act ? t : 0;              // clamped LDS read slot

  const float* WencP = wsP;
  const float* WC0   = wsP + OFF_WC0;
  const float* W1S   = wsP + OFF_W1S;
  const float* W1H   = wsP + OFF_W1H;
  const float* WC0c  = wsP + OFF_WC0c;
  const float* W1c   = wsP + OFF_W1c;

  const float mk = mask[gc];

  // ================= phase 1: h0 = tanh(obs @ W_enc + b_enc) =================
  float acc[HID];
  #pragma unroll
  for (int j = 0; j < HID; j++) acc[j] = b_enc[j];
  {
    const float4* o4 = (const float4*)(obs + gc * OBS_D);
    #pragma unroll 2
    for (int k4 = 0; k4 < OBS_D / 4; k4++) {
      float4 v = o4[k4];
      const float* wr = &WencP[k4 * 4 * LD];
      #pragma unroll
      for (int j = 0; j < HID; j++) acc[j] = fmaf(v.x, wr[j], acc[j]);
      #pragma unroll
      for (int j = 0; j < HID; j++) acc[j] = fmaf(v.y, wr[LD + j], acc[j]);
      #pragma unroll
      for (int j = 0; j < HID; j++) acc[j] = fmaf(v.z, wr[2 * LD + j], acc[j]);
      #pragma unroll
      for (int j = 0; j < HID; j++) acc[j] = fmaf(v.w, wr[3 * LD + j], acc[j]);
    }
  }

  // tanh -> h0 into LDS (lane-private), fused comm-head (step 0) accumulation
  float cl[NSYM];
  #pragma unroll
  for (int s = 0; s < NSYM; s++) cl[s] = b_comm[s];
  if (act) {
    float* myh = &hbuf[t * 51];
    #pragma unroll
    for (int j = 0; j < HID; j++) {
      float h = fast_tanh(acc[j]);
      myh[j] = h;
      const float* wc = &W_comm[j * NSYM];
      #pragma unroll
      for (int s = 0; s < NSYM; s++) cl[s] = fmaf(h, wc[s], cl[s]);
    }
  }

  float clp = 0.f;

  // ---- step 0: pick symbol, aggregate c via wave ballot (no LDS, no barrier)
  int w = comm_pick(cl, mk, clp);
  const int sh = bel * NAGENT;
  float c_reg[NSYM];
  #pragma unroll
  for (int s = 0; s < NSYM; s++) {
    unsigned long long b = __ballot(w == s);
    c_reg[s] = ((b >> sh) & 0x3FFULL) ? 1.f : 0.f;
  }

  // ---- double matmul over h0 (streamed from LDS):
  //      acc  = b_f0 + h0 @ (W_f0[h]+W_f0[skip])   (step-0 h + skip, since h==h0)
  //      pre1 = b_f1 + h0 @ W_f1[skip]             (step-1 skip, h0 dead afterwards)
  float pre1[HID];
  #pragma unroll
  for (int j = 0; j < HID; j++) acc[j]  = b_f[j];
  #pragma unroll
  for (int j = 0; j < HID; j++) pre1[j] = b_f[HID + j];
  {
    const float* myh = &hbuf[sl * 51];
    #pragma unroll 2
    for (int k = 0; k < HID; k++) {
      float x = myh[k];
      const float* w0 = &WC0[k * LD];
      const float* w1 = &W1S[k * LD];
      #pragma unroll
      for (int j = 0; j < HID; j++) acc[j]  = fmaf(x, w0[j], acc[j]);
      #pragma unroll
      for (int j = 0; j < HID; j++) pre1[j] = fmaf(x, w1[j], pre1[j]);
    }
  }
  // step-0 c contribution
  #pragma unroll
  for (int s = 0; s < NSYM; s++) {
    float cv = c_reg[s];
    const float* wr = &WC0c[s * LD];
    #pragma unroll
    for (int j = 0; j < HID; j++) acc[j] = fmaf(cv, wr[j], acc[j]);
  }

  // tanh -> h1 overwrites h0's LDS slot (lane-private, no sync needed),
  // fused comm-head (step 1)
  #pragma unroll
  for (int s = 0; s < NSYM; s++) cl[s] = b_comm[s];
  if (act) {
    float* myh = &hbuf[t * 51];
    #pragma unroll
    for (int j = 0; j < HID; j++) {
      float h = fast_tanh(acc[j]);
      myh[j] = h;
      const float* wc = &W_comm[j * NSYM];
      #pragma unroll
      for (int s = 0; s < NSYM; s++) cl[s] = fmaf(h, wc[s], cl[s]);
    }
  }

  // ---- step 1: pick symbol, aggregate c (this c is also the kernel output)
  w = comm_pick(cl, mk, clp);
  #pragma unroll
  for (int s = 0; s < NSYM; s++) {
    unsigned long long b = __ballot(w == s);
    c_reg[s] = ((b >> sh) & 0x3FFULL) ? 1.f : 0.f;
  }

  // step-1 c contribution + h1 contribution (streamed from LDS) into pre1
  #pragma unroll
  for (int s = 0; s < NSYM; s++) {
    float cv = c_reg[s];
    const float* wr = &W1c[s * LD];
    #pragma unroll
    for (int j = 0; j < HID; j++) pre1[j] = fmaf(cv, wr[j], pre1[j]);
  }
  {
    const float* myh = &hbuf[sl * 51];
    #pragma unroll 2
    for (int k = 0; k < HID; k++) {
      float x = myh[k];
      const float* wr = &W1H[k * LD];
      #pragma unroll
      for (int j = 0; j < HID; j++) pre1[j] = fmaf(x, wr[j], pre1[j]);
    }
  }

  // ---- heads fused with final tanh: h2[j] never materializes as an array
  float l0 = b_pi[0], l1 = b_pi[1], bv = b_v[0];
  #pragma unroll
  for (int j = 0; j < HID; j++) {
    float h = fast_tanh(pre1[j]);
    l0 = fmaf(h, W_pi[j * NACT + 0], l0);
    l1 = fmaf(h, W_pi[j * NACT + 1], l1);
    bv = fmaf(h, W_v[j], bv);
  }

  if (act) {
    float2* o2 = (float2*)out;
    o2[g] = make_float2((mk == 0.f) ? NEGV : l0, (mk == 0.f) ? NEGV : l1);
    out[NA * 2 + g] = bv * mk;
    out[NA * 3 + g] = clp;
    float2* c2 = (float2*)(out + NA * 4);
    const long long cb = g * (NSYM / 2);
    #pragma unroll
    for (int s = 0; s < NSYM / 2; s++)
      c2[cb + s] = make_float2(c_reg[2 * s], c_reg[2 * s + 1]);
  }
}

extern "C" void kernel_launch(void* const* d_in, const int* in_sizes, int n_in,
                              void* d_out, int out_size, void* d_ws, size_t ws_size,
                              hipStream_t stream) {
  const float* obs    = (const float*)d_in[0];
  const float* mask   = (const float*)d_in[1];
  const float* W_enc  = (const float*)d_in[2];
  const float* b_enc  = (const float*)d_in[3];
  const float* W_f    = (const float*)d_in[4];
  const float* b_f    = (const float*)d_in[5];
  const float* W_comm = (const float*)d_in[6];
  const float* b_comm = (const float*)d_in[7];
  const float* W_pi   = (const float*)d_in[8];
  const float* b_pi   = (const float*)d_in[9];
  const float* W_v    = (const float*)d_in[10];
  const float* b_v    = (const float*)d_in[11];
  float* out = (float*)d_out;
  float* ws  = (float*)d_ws;

  const int B = in_sizes[0] / (NAGENT * OBS_D);

  hipLaunchKernelGGL(prep_weights, dim3((NPREP + 255) / 256), dim3(256), 0, stream,
                     W_enc, W_f, ws);

  const int grid = (B + BPB - 1) / BPB;
  hipLaunchKernelGGL(policy_kernel, dim3(grid), dim3(TPB), 0, stream,
                     obs, mask, b_enc, b_f, W_comm, b_comm, W_pi, b_pi, W_v, b_v,
                     ws, out, B);
}